// Round 6
// baseline (10675.282 us; speedup 1.0000x reference)
//
#include <hip/hip_runtime.h>
#include <hip/hip_fp16.h>

typedef __attribute__((ext_vector_type(8))) short short8;
typedef __attribute__((ext_vector_type(4))) float floatx4;

#define DEVFN static __device__ __forceinline__

DEVFN short f2h(float v) { return __half_as_short(__float2half(v)); }

// Fragment-major (FM) layout: matrix [R][K] stored as 16x32 blocks of 512 fp16.
// block (rblk,kblk) at ((rblk*(K/32)+kblk)*512); inner = l4*128 + l15*8 + e
// where l4=(k>>3)&3, l15=r&15, e=k&7. One wave b128-read of a block, with
// lane = l4*16+l15, is a contiguous 1 KB load == MFMA fragment order.
DEVFN long fmblk(int rblk, int kblk, int nkblk) {
  return (((long)rblk * nkblk + kblk) << 9);
}

// Persistent kernel: 81 phases, layer-pipelined (L0(t) || L1(t-1)).
// Zero LDS / zero barriers in the K-loop: A and W fragments are loaded
// directly global->VGPR (coalesced 1 KB) from FM-layout buffers, double-
// buffered one kb (K=64) ahead. Per-batch-group barrier between phases.
// Grid (64,8): bx<32 -> L0 (u-tile bx), bx>=32 -> L1 (u-tile bx-32).
__global__ __launch_bounds__(256, 2) void pers_kernel(
    short* xe0, short* xe1, short* xd0, short* xd1,
    const short* wc_e0, const short* wc_e1, const short* wc_d0, const short* wc_d1,
    const float* eb0, const float* eb1, const float* db0, const float* db1,
    const short* embe, const short* embd,
    const int* __restrict__ src, const int* __restrict__ tgt,
    short* dh1, unsigned* cells) {
  __shared__ short ht[128 * 40];  // h transpose tile only (10 KB)
  const int tid = threadIdx.x;
  const int lane = tid & 63;
  const int wv = tid >> 6;   // 0..3
  const int wm = wv >> 1;    // 64-row group
  const int wu = wv & 1;     // 16-unit group
  const int l15 = lane & 15;
  const int ll4 = lane >> 4; // 0..3
  const int bx = blockIdx.x;
  const int role1 = bx >> 5;
  const int u0 = (bx & 31) * 32;
  const int gy = blockIdx.y;
  const int m0 = gy * 128;
  const long SL0 = 1024l * 1280, SL1 = 1024l * 2048;
  const int lane8 = lane * 8;

  float cst[16];
#pragma unroll
  for (int i = 0; i < 16; ++i) cst[i] = 0.f;

  for (int p = 0; p < 81; ++p) {
    // ---- per-group barrier (64 blocks sharing gy) ----
    if (p) {
      __syncthreads();
      unsigned* gc = cells + (((long)p * 8 + gy) << 6);
      if (tid == 0)
        __hip_atomic_store(gc + bx, 1u, __ATOMIC_RELEASE, __HIP_MEMORY_SCOPE_AGENT);
      if (tid < 64) {
        while (__hip_atomic_load(gc + tid, __ATOMIC_RELAXED,
                                 __HIP_MEMORY_SCOPE_AGENT) == 0u)
          __builtin_amdgcn_s_sleep(1);
        (void)__hip_atomic_load(gc + tid, __ATOMIC_ACQUIRE, __HIP_MEMORY_SCOPE_AGENT);
      }
      __syncthreads();
    }

    // ---- phase role decode ----
    int active, t;
    const int isdec = (p > 32);
    if (!role1) {
      if (!isdec) { active = (p < 32); t = p; }
      else        { active = (p <= 79); t = p - 33; }
    } else {
      if (!isdec) { active = (p >= 1); t = p - 1; }
      else        { active = (p >= 34); t = p - 34; }
    }
    if (!active) continue;

    const int cur = t & 1, nxt = cur ^ 1;
    const short* A; const short* Wt; const float* bs; int ktot;
    short *d1 = nullptr, *d2 = nullptr, *d3 = nullptr, *xq = nullptr;
    int s1 = 0, o1 = 0, xs = 0;
    const short* xe = nullptr; const int* tk = nullptr;
    if (!role1) {
      if (!isdec) {
        A = xe0 + cur * SL0; Wt = wc_e0; bs = eb0; ktot = 1280;
        d2 = xe1 + cur * SL1;
        s1 = 1280; o1 = 256; xs = 1280;
        if (t < 31) { d1 = xe0 + nxt * SL0; xq = d1; xe = embe; tk = src + (t + 1) * 1024; }
        else        { d1 = xd0;             xq = xd0; xe = embd; tk = tgt; }
      } else {
        A = xd0 + cur * SL0; Wt = wc_d0; bs = db0; ktot = 1280;
        d1 = xd0 + nxt * SL0; s1 = 1280; o1 = 256;
        d2 = xd1 + cur * SL1;
        xq = xd0 + nxt * SL0; xs = 1280; xe = embd; tk = tgt + (t + 1) * 1024;
      }
    } else {
      if (!isdec) {
        A = xe1 + cur * SL1; Wt = wc_e1; bs = eb1; ktot = 2048;
        d1 = (t < 31) ? (xe1 + nxt * SL1) : xd1; s1 = 2048; o1 = 1024;
      } else {
        A = xd1 + cur * SL1; Wt = wc_d1; bs = db1; ktot = 2048;
        d1 = xd1 + nxt * SL1; s1 = 2048; o1 = 1024;
        d3 = dh1 + (long)t * 1024 * 1024;
      }
    }

    // ---- GEMM: direct FM global->reg, double-buffered, no LDS/no barrier ----
    floatx4 acc[4][4];
#pragma unroll
    for (int g = 0; g < 4; ++g)
#pragma unroll
      for (int mi = 0; mi < 4; ++mi) acc[g][mi] = (floatx4){0.f, 0.f, 0.f, 0.f};

    const int nkblk = ktot >> 5;       // 32-k blocks per row-block
    const int nkb = ktot >> 6;         // K=64 steps
    const int arblk = (m0 >> 4) + wm * 4;      // + mi
    const int wrblk = (u0 >> 4) + wu;          // + g*64

    short8 a0[8], w0[8], a1[8], w1[8];

#define LOADT(AB, WB, kb)                                                      \
  do {                                                                         \
    _Pragma("unroll") for (int mi = 0; mi < 4; ++mi)                           \
      _Pragma("unroll") for (int h = 0; h < 2; ++h)                            \
        AB[mi * 2 + h] =                                                       \
            *(const short8*)(A + fmblk(arblk + mi, (kb) * 2 + h, nkblk) + lane8); \
    _Pragma("unroll") for (int g = 0; g < 4; ++g)                              \
      _Pragma("unroll") for (int h = 0; h < 2; ++h)                            \
        WB[g * 2 + h] =                                                        \
            *(const short8*)(Wt + fmblk(wrblk + g * 64, (kb) * 2 + h, nkblk) + lane8); \
  } while (0)

#define MFMAT(AB, WB)                                                          \
  do {                                                                         \
    _Pragma("unroll") for (int h = 0; h < 2; ++h)                              \
      _Pragma("unroll") for (int g = 0; g < 4; ++g)                            \
        _Pragma("unroll") for (int mi = 0; mi < 4; ++mi)                       \
          asm volatile("v_mfma_f32_16x16x32_f16 %0, %1, %2, %0"                \
                       : "+v"(acc[g][mi])                                      \
                       : "v"(AB[mi * 2 + h]), "v"(WB[g * 2 + h]));             \
  } while (0)

    LOADT(a0, w0, 0);
    int kb = 0;
    while (true) {
      if (kb + 1 < nkb) LOADT(a1, w1, kb + 1);
      MFMAT(a0, w0);
      ++kb; if (kb >= nkb) break;
      if (kb + 1 < nkb) LOADT(a0, w0, kb + 1);
      MFMAT(a1, w1);
      ++kb; if (kb >= nkb) break;
    }
#undef LOADT
#undef MFMAT
    asm volatile("s_nop 7\ns_nop 7\ns_nop 7");  // MFMA -> VALU hazard guard

    // ---- LSTM cell (c in regs) -> h into LDS transpose tile ----
    const int u = u0 + wu * 16 + l15;
    const float bi = bs[u];
    const float bf_ = bs[1024 + u];
    const float bg = bs[2048 + u];
    const float bo = bs[3072 + u];
    const int uloc = wu * 16 + l15;
#pragma unroll
    for (int mi = 0; mi < 4; ++mi) {
#pragma unroll
      for (int j = 0; j < 4; ++j) {
        const float zi = acc[0][mi][j] + bi;
        const float zf = acc[1][mi][j] + bf_;
        const float zg = acc[2][mi][j] + bg;
        const float zo = acc[3][mi][j] + bo;
        const float gi = 1.f / (1.f + expf(-zi));
        const float gf = 1.f / (1.f + expf(-zf));
        const float gg = tanhf(zg);
        const float go = 1.f / (1.f + expf(-zo));
        const float cn = gf * cst[mi * 4 + j] + gi * gg;
        cst[mi * 4 + j] = cn;
        const int rl = wm * 64 + mi * 16 + ll4 * 4 + j;
        ht[rl * 40 + uloc] = f2h(go * tanhf(cn));
      }
    }
    __syncthreads();

    // ---- h writes: FM blocks, contiguous 32 B per thread per dest ----
    {
      const int rb = tid >> 5;        // 0..7 row-block
      const int c = tid & 31;
      const int l4w = c >> 3;         // unit-octet
      const int pr = c & 7;           // row-pair
      const int r0 = rb * 16 + pr * 2;
      const short8 v0 = *(const short8*)(ht + r0 * 40 + l4w * 8);
      const short8 v1 = *(const short8*)(ht + (r0 + 1) * 40 + l4w * 8);
      const int rgb = (m0 >> 4) + rb;
      const int inner = l4w * 128 + pr * 16;
      if (d1) {
        long ix = fmblk(rgb, (o1 + u0) >> 5, s1 >> 5) + inner;
        *(short8*)(d1 + ix) = v0; *(short8*)(d1 + ix + 8) = v1;
      }
      if (d2) {
        long ix = fmblk(rgb, u0 >> 5, 64) + inner;
        *(short8*)(d2 + ix) = v0; *(short8*)(d2 + ix + 8) = v1;
      }
      if (d3) {
        long ix = fmblk(rgb, u0 >> 5, 32) + inner;
        *(short8*)(d3 + ix) = v0; *(short8*)(d3 + ix + 8) = v1;
      }
    }
    // ---- next-step embedding gather -> FM x-region (u-tile-0 L0 blocks) ----
    if (xq && bx == 0) {
      const int xnk = xs >> 5;
      for (int i = tid; i < 4096; i += 256) {
        const int bl = i >> 5;        // 0..127 local row
        const int c = i & 31;         // 8-fp16 chunk within 256 emb
        const int tok = tk[m0 + bl];
        const short8 v = *(const short8*)(xe + (long)tok * 256 + c * 8);
        long ix = fmblk((m0 + bl) >> 4, c >> 2, xnk) + (c & 3) * 128 + (bl & 15) * 8;
        *(short8*)(xq + ix) = v;
      }
    }
  }
}

// fc projection: out[1:] = dh1 @ fcWt^T + fc_b. Direct FM loads, no LDS.
__global__ __launch_bounds__(256) void fc_kernel(
    const short* __restrict__ A, const short* __restrict__ W,
    const float* __restrict__ bias, float* __restrict__ outp) {
  const int tid = threadIdx.x;
  const int lane = tid & 63;
  const int wv = tid >> 6;
  const int wm = wv >> 1;
  const int wu = wv & 1;
  const int l15 = lane & 15;
  const int ll4 = lane >> 4;
  const int u0 = blockIdx.x * 128;
  const int m0 = blockIdx.y * 128;
  const int lane8 = lane * 8;

  floatx4 acc[4][4];
#pragma unroll
  for (int g = 0; g < 4; ++g)
#pragma unroll
    for (int mi = 0; mi < 4; ++mi) acc[g][mi] = (floatx4){0.f, 0.f, 0.f, 0.f};

  const int nkblk = 32, nkb = 16;
  const int arblk = (m0 >> 4) + wm * 4;
  const int wrblk = (u0 >> 4) + wu;  // + g*2

  short8 a0[8], w0[8], a1[8], w1[8];
#define LOADT(AB, WB, kb)                                                      \
  do {                                                                         \
    _Pragma("unroll") for (int mi = 0; mi < 4; ++mi)                           \
      _Pragma("unroll") for (int h = 0; h < 2; ++h)                            \
        AB[mi * 2 + h] =                                                       \
            *(const short8*)(A + fmblk(arblk + mi, (kb) * 2 + h, nkblk) + lane8); \
    _Pragma("unroll") for (int g = 0; g < 4; ++g)                              \
      _Pragma("unroll") for (int h = 0; h < 2; ++h)                            \
        WB[g * 2 + h] =                                                        \
            *(const short8*)(W + fmblk(wrblk + g * 2, (kb) * 2 + h, nkblk) + lane8); \
  } while (0)
#define MFMAT(AB, WB)                                                          \
  do {                                                                         \
    _Pragma("unroll") for (int h = 0; h < 2; ++h)                              \
      _Pragma("unroll") for (int g = 0; g < 4; ++g)                            \
        _Pragma("unroll") for (int mi = 0; mi < 4; ++mi)                       \
          asm volatile("v_mfma_f32_16x16x32_f16 %0, %1, %2, %0"                \
                       : "+v"(acc[g][mi])                                      \
                       : "v"(AB[mi * 2 + h]), "v"(WB[g * 2 + h]));             \
  } while (0)
  LOADT(a0, w0, 0);
  int kb = 0;
  while (true) {
    if (kb + 1 < nkb) LOADT(a1, w1, kb + 1);
    MFMAT(a0, w0);
    ++kb; if (kb >= nkb) break;
    if (kb + 1 < nkb) LOADT(a0, w0, kb + 1);
    MFMAT(a1, w1);
    ++kb; if (kb >= nkb) break;
  }
#undef LOADT
#undef MFMAT
  asm volatile("s_nop 7\ns_nop 7\ns_nop 7");

#pragma unroll
  for (int g = 0; g < 4; ++g) {
    const int n = u0 + g * 32 + wu * 16 + l15;
    const float bb = bias[n];
#pragma unroll
    for (int mi = 0; mi < 4; ++mi) {
#pragma unroll
      for (int j = 0; j < 4; ++j) {
        const int r = m0 + wm * 64 + mi * 16 + ll4 * 4 + j;
        outp[(long)r * 256 + n] = acc[g][mi][j] + bb;
      }
    }
  }
}

// weights -> fp16 FM layout, [Wih | Whh] concat along K, gate-major rows
__global__ void wprep(const float* __restrict__ A, const float* __restrict__ B,
                      short* __restrict__ dst, int N, int Ka, int Kb) {
  const int ktot = Ka + Kb;
  const int n8 = ktot >> 3;
  const int total = N * n8;
  const int nkblk = ktot >> 5;
  for (int idx = blockIdx.x * 256 + threadIdx.x; idx < total; idx += gridDim.x * 256) {
    const int n = idx / n8;
    const int k = (idx - n * n8) * 8;
    const float* s = (k < Ka) ? (A + (long)n * Ka + k) : (B + (long)n * Kb + (k - Ka));
    short8 v;
#pragma unroll
    for (int j = 0; j < 8; ++j) v[j] = f2h(s[j]);
    long ix = fmblk(n >> 4, k >> 5, nkblk) + ((k >> 3) & 3) * 128 + (n & 15) * 8;
    *(short8*)(dst + ix) = v;
  }
}

// embedding tables -> linear fp16 (gather reads rows contiguously)
__global__ void embprep(const float* __restrict__ s, short* __restrict__ d, int total8) {
  const int idx = blockIdx.x * 256 + threadIdx.x;
  if (idx >= total8) return;
  short8 v;
#pragma unroll
  for (int j = 0; j < 8; ++j) v[j] = f2h(s[idx * 8 + j]);
  *(short8*)(d + idx * 8) = v;
}

// fc_W [1024][256] -> W'[v][h] = fcW[h][v], fp16 FM (K=1024)
__global__ void fcwprep(const float* __restrict__ fcW, short* __restrict__ dst) {
  const int idx = blockIdx.x * 256 + threadIdx.x;  // 32768
  const int v = idx & 255;
  const int h = (idx >> 8) * 8;
  short8 o;
#pragma unroll
  for (int j = 0; j < 8; ++j) o[j] = f2h(fcW[(long)(h + j) * 256 + v]);
  long ix = fmblk(v >> 4, h >> 5, 32) + ((h >> 3) & 3) * 128 + (v & 15) * 8;
  *(short8*)(dst + ix) = o;
}

// xe0 slot0: x = enc_emb[src[0]] (FM), h-region = 0; xe1 slot0 h-half = 0
__global__ void initk(const int* __restrict__ src, const float* __restrict__ emb,
                      short* __restrict__ xe0, short* __restrict__ xe1) {
  const int idx = blockIdx.x * 256 + threadIdx.x;
  if (idx < 1024 * 160) {
    const int b = idx / 160;
    const int k = (idx - b * 160) * 8;
    short8 v;
    if (k < 256) {
      const int tok = src[b];
#pragma unroll
      for (int j = 0; j < 8; ++j) v[j] = f2h(emb[(long)tok * 256 + k + j]);
    } else {
#pragma unroll
      for (int j = 0; j < 8; ++j) v[j] = 0;
    }
    long ix = fmblk(b >> 4, k >> 5, 40) + ((k >> 3) & 3) * 128 + (b & 15) * 8;
    *(short8*)(xe0 + ix) = v;
  } else {
    const int i = idx - 1024 * 160;
    if (i < 1024 * 128) {
      const int b = i >> 7;
      const int k = 1024 + (i & 127) * 8;
      short8 v;
#pragma unroll
      for (int j = 0; j < 8; ++j) v[j] = 0;
      long ix = fmblk(b >> 4, k >> 5, 64) + ((k >> 3) & 3) * 128 + (b & 15) * 8;
      *(short8*)(xe1 + ix) = v;
    }
  }
}

extern "C" void kernel_launch(void* const* d_in, const int* in_sizes, int n_in,
                              void* d_out, int out_size, void* d_ws, size_t ws_size,
                              hipStream_t stream) {
  (void)in_sizes; (void)n_in; (void)out_size; (void)ws_size;
  const int* src = (const int*)d_in[0];
  const int* tgt = (const int*)d_in[1];
  const float* enc_emb = (const float*)d_in[2];
  const float* eW0i = (const float*)d_in[3];
  const float* eW0h = (const float*)d_in[4];
  const float* eb0 = (const float*)d_in[5];
  const float* eW1i = (const float*)d_in[6];
  const float* eW1h = (const float*)d_in[7];
  const float* eb1 = (const float*)d_in[8];
  const float* dec_emb = (const float*)d_in[9];
  const float* dW0i = (const float*)d_in[10];
  const float* dW0h = (const float*)d_in[11];
  const float* db0 = (const float*)d_in[12];
  const float* dW1i = (const float*)d_in[13];
  const float* dW1h = (const float*)d_in[14];
  const float* db1 = (const float*)d_in[15];
  const float* fcW = (const float*)d_in[16];
  const float* fcb = (const float*)d_in[17];
  float* out = (float*)d_out;

  char* ws = (char*)d_ws;
  size_t off = 0;
  auto carve = [&](size_t bytes) {
    void* p = ws + off;
    off += (bytes + 255) & ~(size_t)255;
    return p;
  };
  short* wc_e0 = (short*)carve(4096l * 1280 * 2);
  short* wc_e1 = (short*)carve(4096l * 2048 * 2);
  short* wc_d0 = (short*)carve(4096l * 1280 * 2);
  short* wc_d1 = (short*)carve(4096l * 2048 * 2);
  short* fcwt = (short*)carve(256l * 1024 * 2);
  short* embe = (short*)carve(256l * 256 * 2);
  short* embd = (short*)carve(256l * 256 * 2);
  short* xe0 = (short*)carve(2l * 1024 * 1280 * 2);
  short* xe1 = (short*)carve(2l * 1024 * 2048 * 2);
  short* xd0 = (short*)carve(2l * 1024 * 1280 * 2);
  short* xd1 = (short*)carve(2l * 1024 * 2048 * 2);
  short* dh1 = (short*)carve(47l * 1024 * 1024 * 2);
  unsigned* cells = (unsigned*)carve(81l * 8 * 64 * 4);

  hipMemsetAsync(cells, 0, 81l * 8 * 64 * 4, stream);
  hipMemsetAsync(out, 0, 1024l * 256 * 4, stream);  // outputs[0] stays zeros

  wprep<<<2560, 256, 0, stream>>>(eW0i, eW0h, wc_e0, 4096, 256, 1024);
  wprep<<<4096, 256, 0, stream>>>(eW1i, eW1h, wc_e1, 4096, 1024, 1024);
  wprep<<<2560, 256, 0, stream>>>(dW0i, dW0h, wc_d0, 4096, 256, 1024);
  wprep<<<4096, 256, 0, stream>>>(dW1i, dW1h, wc_d1, 4096, 1024, 1024);
  embprep<<<32, 256, 0, stream>>>(enc_emb, embe, 8192);
  embprep<<<32, 256, 0, stream>>>(dec_emb, embd, 8192);
  fcwprep<<<128, 256, 0, stream>>>(fcW, fcwt);
  initk<<<1152, 256, 0, stream>>>(src, enc_emb, xe0, xe1);

  pers_kernel<<<dim3(64, 8), 256, 0, stream>>>(
      xe0, xe1, xd0, xd1, wc_e0, wc_e1, wc_d0, wc_d1,
      eb0, eb1, db0, db1, embe, embd, src, tgt, dh1, cells);

  fc_kernel<<<dim3(2, 376), 256, 0, stream>>>(dh1, fcwt, fcb, out + 1024l * 256);
}

// Round 7
// 4210.032 us; speedup vs baseline: 2.5357x; 2.5357x over previous
//
#include <hip/hip_runtime.h>
#include <hip/hip_fp16.h>

typedef __attribute__((ext_vector_type(8))) short short8;
typedef __attribute__((ext_vector_type(4))) float floatx4;

#define DEVFN static __device__ __forceinline__

DEVFN short f2h(float v) { return __half_as_short(__float2half(v)); }

DEVFN void gload16(const void* g, void* l) {
  void* gnc = const_cast<void*>(g);
  __builtin_amdgcn_global_load_lds(
      (__attribute__((address_space(1))) void*)gnc,
      (__attribute__((address_space(3))) void*)l, 16, 0, 0);
}

// flag set for (role, s, gy): 32 cells, one per u-tile block
DEVFN unsigned* fset(unsigned* f, int role, int s, int gy) {
  return f + ((((role * 79) + s) * 8 + gy) << 5);
}

// Persistent dataflow kernel: 79 sequential steps per role, point-to-point
// flag sync (no barriers):  L1(s) <- {L0(s), L1(s-1)};  L0(s) <- {L0(s-1),
// L1(s-2)}  (lag-2 = anti-dep on the h0-half slot L1(s-2) reads).
// Grid (64,8): bx<32 -> L0 (u-tile bx), bx>=32 -> L1 (u-tile bx-32).
// Block = 32 units x 128 batch rows, fixed forever -> c-state in registers.
__global__ __launch_bounds__(256, 2) void pers_kernel(
    short* xe0, short* xe1, short* xd0, short* xd1,
    const short* wc_e0, const short* wc_e1, const short* wc_d0, const short* wc_d1,
    const float* eb0, const float* eb1, const float* db0, const float* db1,
    const short* embe, const short* embd,
    const int* __restrict__ src, const int* __restrict__ tgt,
    short* dh1, unsigned* flags) {
  __shared__ short smem[32768];  // 2 buffers x (A 128x64 | W 128x64) fp16 = 64 KB
  const int tid = threadIdx.x;
  const int lane = tid & 63;
  const int wv = tid >> 6;   // 0..3
  const int wm = wv >> 1;    // 64-row group
  const int wu = wv & 1;     // 16-unit group
  const int l15 = lane & 15;
  const int l4 = lane >> 4;
  const int bx = blockIdx.x;
  const int role1 = bx >> 5;
  const int ut = bx & 31;
  const int u0 = ut * 32;
  const int gy = blockIdx.y;
  const int m0 = gy * 128;
  const int srow = lane >> 3;
  const int swseg = ((lane & 7) * 16) ^ (srow * 16);  // source-side LDS swizzle
  const long SL0 = 1024l * 1280, SL1 = 1024l * 2048;

  float cst[16];
#pragma unroll
  for (int i = 0; i < 16; ++i) cst[i] = 0.f;

  for (int s = 0; s < 79; ++s) {
    // ---- dependency wait (wave-0 lanes poll producer cells) ----
    unsigned* WA = nullptr;
    unsigned* WB = nullptr;
    if (!role1) {
      if (s >= 1) WA = fset(flags, 0, s - 1, gy);
      if (s >= 2) WB = fset(flags, 1, s - 2, gy);
    } else {
      WA = fset(flags, 0, s, gy);
      if (s >= 1) WB = fset(flags, 1, s - 1, gy);
    }
    if (WA || WB) {
      if (tid < 64) {
        unsigned* p = (tid < 32) ? (WA ? WA + tid : nullptr)
                                 : (WB ? WB + (tid - 32) : nullptr);
        if (p) {
          while (__hip_atomic_load(p, __ATOMIC_RELAXED,
                                   __HIP_MEMORY_SCOPE_AGENT) == 0u)
            __builtin_amdgcn_s_sleep(1);
          (void)__hip_atomic_load(p, __ATOMIC_ACQUIRE, __HIP_MEMORY_SCOPE_AGENT);
        }
      }
      __syncthreads();
    }

    // ---- step params ----
    const int enc = (s < 32) ? 1 : 0;
    const int t = enc ? s : s - 32;          // dec t = 0..46
    const int cur = t & 1, nxt = cur ^ 1;
    const short* A; const short* Wt; const float* bs; int ktot;
    short *d1 = nullptr, *d2 = nullptr, *d3 = nullptr, *xq = nullptr;
    int s1 = 0, o1 = 0, xs = 0;
    const short* xe = nullptr; const int* tk = nullptr;
    if (!role1) {
      if (enc) {
        A = xe0 + cur * SL0; Wt = wc_e0; bs = eb0; ktot = 1280;
        d2 = xe1 + cur * SL1;                 // hs0[t] -> enc L1 input (s=2048,o=0)
        s1 = 1280; o1 = 256; xs = 1280;
        if (t < 31) { d1 = xe0 + nxt * SL0; xq = d1; xe = embe; tk = src + (t + 1) * 1024; }
        else        { d1 = xd0;             xq = xd0; xe = embd; tk = tgt; }
      } else {
        A = xd0 + cur * SL0; Wt = wc_d0; bs = db0; ktot = 1280;
        d1 = xd0 + nxt * SL0; s1 = 1280; o1 = 256;
        d2 = xd1 + cur * SL1;                 // dh0 -> dec L1 input
        if (t < 46) { xq = xd0 + nxt * SL0; xs = 1280; xe = embd; tk = tgt + (t + 1) * 1024; }
      }
    } else {
      if (enc) {
        A = xe1 + cur * SL1; Wt = wc_e1; bs = eb1; ktot = 2048;
        d1 = (t < 31) ? (xe1 + nxt * SL1) : xd1; s1 = 2048; o1 = 1024;
      } else {
        A = xd1 + cur * SL1; Wt = wc_d1; bs = db1; ktot = 2048;
        d1 = xd1 + nxt * SL1; s1 = 2048; o1 = 1024;
        d3 = dh1 + (long)t * 1024 * 1024;     // archive dh1[t] (s=1024,o=0)
      }
    }

    // ---- GEMM: z = A @ W^T, 2-buffer LDS pipeline (R5-proven) ----
    floatx4 acc[4][4];
#pragma unroll
    for (int g = 0; g < 4; ++g)
#pragma unroll
      for (int mi = 0; mi < 4; ++mi) acc[g][mi] = (floatx4){0.f, 0.f, 0.f, 0.f};

    const char* Ab = (const char*)A;
    const char* Wb = (const char*)Wt;
    const long kbytes = (long)ktot * 2;
    const int nkb = ktot >> 6;

    auto stage = [&](int kb, int bufi) {
      const long kboff = (long)kb * 128;
      short* sb = smem + bufi * 16384;
#pragma unroll
      for (int ci = 0; ci < 8; ++ci) {
        const int c = wv * 8 + ci;
        void* lds = (void*)(sb + c * 512);
        if (c < 16) {  // A chunks
          const int row = c * 8 + srow;
          gload16(Ab + (long)(m0 + row) * kbytes + kboff + swseg, lds);
        } else {       // W chunks: 4 gates x 32 units
          const int cb = c - 16;
          const int wrow = (cb >> 2) * 1024 + u0 + (cb & 3) * 8 + srow;
          gload16(Wb + (long)wrow * kbytes + kboff + swseg, lds);
        }
      }
    };

    stage(0, 0);
    __syncthreads();
    int buf = 0;
    for (int kb = 0; kb < nkb; ++kb) {
      if (kb + 1 < nkb) stage(kb + 1, buf ^ 1);  // prefetch under compute
      const short* sb = smem + buf * 16384;
#pragma unroll
      for (int k0 = 0; k0 < 64; k0 += 32) {
        short8 fa[4];
        short8 fb[4];
#pragma unroll
        for (int mi = 0; mi < 4; ++mi) {
          const int r = wm * 64 + mi * 16 + l15;
          fa[mi] = *(const short8*)(sb + r * 64 + ((k0 + l4 * 8) ^ ((r & 7) << 3)));
        }
        {
          const int r = wu * 16 + l15;
          const int kk = (k0 + l4 * 8) ^ ((r & 7) << 3);
#pragma unroll
          for (int g = 0; g < 4; ++g)
            fb[g] = *(const short8*)(sb + 8192 + (g * 32 + r) * 64 + kk);
        }
#pragma unroll
        for (int g = 0; g < 4; ++g)
#pragma unroll
          for (int mi = 0; mi < 4; ++mi)
            asm volatile("v_mfma_f32_16x16x32_f16 %0, %1, %2, %0"
                         : "+v"(acc[g][mi])
                         : "v"(fa[mi]), "v"(fb[g]));
      }
      __syncthreads();
      buf ^= 1;
    }
    asm volatile("s_nop 7\ns_nop 7\ns_nop 7");  // MFMA -> VALU hazard guard

    // ---- LSTM cell (c in regs) -> h into LDS transpose tile ----
    const int u = u0 + wu * 16 + l15;
    const float bi = bs[u];
    const float bf_ = bs[1024 + u];
    const float bg = bs[2048 + u];
    const float bo = bs[3072 + u];
    short* ht = smem;  // [128][40] fp16, reuses buf0 (all LDS reads done)
    const int uloc = wu * 16 + l15;
#pragma unroll
    for (int mi = 0; mi < 4; ++mi) {
#pragma unroll
      for (int j = 0; j < 4; ++j) {
        const float zi = acc[0][mi][j] + bi;
        const float zf = acc[1][mi][j] + bf_;
        const float zg = acc[2][mi][j] + bg;
        const float zo = acc[3][mi][j] + bo;
        const float gi = 1.f / (1.f + expf(-zi));
        const float gf = 1.f / (1.f + expf(-zf));
        const float gg = tanhf(zg);
        const float go = 1.f / (1.f + expf(-zo));
        const float cn = gf * cst[mi * 4 + j] + gi * gg;
        cst[mi * 4 + j] = cn;
        const int rl = wm * 64 + mi * 16 + l4 * 4 + j;
        ht[rl * 40 + uloc] = f2h(go * tanhf(cn));
      }
    }
    __syncthreads();

    // ---- coalesced h writes (32 B/thread per dest) ----
    {
      const int rl = tid >> 1;
      const int seg = (tid & 1) * 16;
      const short8 v0 = *(const short8*)(ht + rl * 40 + seg);
      const short8 v1 = *(const short8*)(ht + rl * 40 + seg + 8);
      const long col = u0 + seg;
      if (d1) {
        short* p = d1 + (long)(m0 + rl) * s1 + o1 + col;
        *(short8*)p = v0; *(short8*)(p + 8) = v1;
      }
      if (d2) {
        short* p = d2 + (long)(m0 + rl) * 2048 + col;
        *(short8*)p = v0; *(short8*)(p + 8) = v1;
      }
      if (d3) {
        short* p = d3 + (long)(m0 + rl) * 1024 + col;
        *(short8*)p = v0; *(short8*)(p + 8) = v1;
      }
    }
    // ---- next-step embedding gather: 128-item slice per L0 block ----
    if (xq && tid < 128) {
      const int i = ut * 128 + tid;
      const int row = i >> 5;
      const int e8 = (i & 31) * 8;
      const int b = m0 + row;
      const int tok = tk[b];
      const short8 v = *(const short8*)(xe + (long)tok * 256 + e8);
      *(short8*)(xq + (long)b * xs + e8) = v;
    }

    // ---- publish: all stores drained (syncthreads), then release flag ----
    __syncthreads();
    if (tid == 0)
      __hip_atomic_store(fset(flags, role1, s, gy) + ut, 1u,
                         __ATOMIC_RELEASE, __HIP_MEMORY_SCOPE_AGENT);
  }
}

// fc projection: out[1:] = dh1_all @ fcWt^T + fc_b
__global__ __launch_bounds__(256) void fc_kernel(
    const short* __restrict__ A, const short* __restrict__ W,
    const float* __restrict__ bias, float* __restrict__ outp) {
  __shared__ short smem[32768];
  const int tid = threadIdx.x;
  const int lane = tid & 63;
  const int wv = tid >> 6;
  const int wm = wv >> 1;
  const int wu = wv & 1;
  const int l15 = lane & 15;
  const int l4 = lane >> 4;
  const int u0 = blockIdx.x * 128;
  const int m0 = blockIdx.y * 128;
  const int srow = lane >> 3;
  const int swseg = ((lane & 7) * 16) ^ (srow * 16);

  floatx4 acc[4][4];
#pragma unroll
  for (int g = 0; g < 4; ++g)
#pragma unroll
    for (int mi = 0; mi < 4; ++mi) acc[g][mi] = (floatx4){0.f, 0.f, 0.f, 0.f};

  const char* Ab = (const char*)A;
  const char* Wb = (const char*)W;
  const long kbytes = 2048;
  const int nkb = 16;

  auto stage = [&](int kb, int bufi) {
    const long kboff = (long)kb * 128;
    short* sb = smem + bufi * 16384;
#pragma unroll
    for (int ci = 0; ci < 8; ++ci) {
      const int c = wv * 8 + ci;
      void* lds = (void*)(sb + c * 512);
      if (c < 16) {
        const int row = c * 8 + srow;
        gload16(Ab + (long)(m0 + row) * kbytes + kboff + swseg, lds);
      } else {
        const int cb = c - 16;
        const int wrow = (cb >> 2) * 32 + u0 + (cb & 3) * 8 + srow;
        gload16(Wb + (long)wrow * kbytes + kboff + swseg, lds);
      }
    }
  };

  stage(0, 0);
  __syncthreads();
  int buf = 0;
  for (int kb = 0; kb < nkb; ++kb) {
    if (kb + 1 < nkb) stage(kb + 1, buf ^ 1);
    const short* sb = smem + buf * 16384;
#pragma unroll
    for (int k0 = 0; k0 < 64; k0 += 32) {
      short8 fa[4];
      short8 fb[4];
#pragma unroll
      for (int mi = 0; mi < 4; ++mi) {
        const int r = wm * 64 + mi * 16 + l15;
        fa[mi] = *(const short8*)(sb + r * 64 + ((k0 + l4 * 8) ^ ((r & 7) << 3)));
      }
      {
        const int r = wu * 16 + l15;
        const int kk = (k0 + l4 * 8) ^ ((r & 7) << 3);
#pragma unroll
        for (int g = 0; g < 4; ++g)
          fb[g] = *(const short8*)(sb + 8192 + (g * 32 + r) * 64 + kk);
      }
#pragma unroll
      for (int g = 0; g < 4; ++g)
#pragma unroll
        for (int mi = 0; mi < 4; ++mi)
          asm volatile("v_mfma_f32_16x16x32_f16 %0, %1, %2, %0"
                       : "+v"(acc[g][mi])
                       : "v"(fa[mi]), "v"(fb[g]));
    }
    __syncthreads();
    buf ^= 1;
  }
  asm volatile("s_nop 7\ns_nop 7\ns_nop 7");

#pragma unroll
  for (int g = 0; g < 4; ++g) {
    const int n = u0 + g * 32 + wu * 16 + l15;
    const float bb = bias[n];
#pragma unroll
    for (int mi = 0; mi < 4; ++mi) {
#pragma unroll
      for (int j = 0; j < 4; ++j) {
        const int r = m0 + wm * 64 + mi * 16 + l4 * 4 + j;
        outp[(long)r * 256 + n] = acc[g][mi][j] + bb;
      }
    }
  }
}

// weights -> fp16, [Wih | Whh] concat along K, gate-major rows, LINEAR layout
__global__ void wprep(const float* __restrict__ A, const float* __restrict__ B,
                      short* __restrict__ dst, int N, int Ka, int Kb) {
  const int ktot = Ka + Kb;
  const int n8 = ktot >> 3;
  const int total = N * n8;
  for (int idx = blockIdx.x * 256 + threadIdx.x; idx < total; idx += gridDim.x * 256) {
    const int n = idx / n8;
    const int k = (idx - n * n8) * 8;
    const float* s = (k < Ka) ? (A + (long)n * Ka + k) : (B + (long)n * Kb + (k - Ka));
    short8 v;
#pragma unroll
    for (int j = 0; j < 8; ++j) v[j] = f2h(s[j]);
    *(short8*)(dst + (long)n * ktot + k) = v;
  }
}

__global__ void embprep(const float* __restrict__ s, short* __restrict__ d, int total8) {
  const int idx = blockIdx.x * 256 + threadIdx.x;
  if (idx >= total8) return;
  short8 v;
#pragma unroll
  for (int j = 0; j < 8; ++j) v[j] = f2h(s[idx * 8 + j]);
  *(short8*)(d + idx * 8) = v;
}

// fc_W [1024][256] -> fcWt [256][1024] fp16, LINEAR
__global__ void fcwprep(const float* __restrict__ fcW, short* __restrict__ dst) {
  const int idx = blockIdx.x * 256 + threadIdx.x;  // 32768
  const int v = idx & 255;
  const int h = (idx >> 8) * 8;
  short8 o;
#pragma unroll
  for (int j = 0; j < 8; ++j) o[j] = f2h(fcW[(long)(h + j) * 256 + v]);
  *(short8*)(dst + (long)v * 1024 + h) = o;
}

// xe0 slot0: x = enc_emb[src[0]], h = 0 ; xe1 slot0 h-half = 0   (LINEAR)
__global__ void initk(const int* __restrict__ src, const float* __restrict__ emb,
                      short* __restrict__ xe0, short* __restrict__ xe1) {
  const int idx = blockIdx.x * 256 + threadIdx.x;
  if (idx < 1024 * 160) {
    const int b = idx / 160;
    const int k = (idx - b * 160) * 8;
    short8 v;
    if (k < 256) {
      const int tok = src[b];
#pragma unroll
      for (int j = 0; j < 8; ++j) v[j] = f2h(emb[(long)tok * 256 + k + j]);
    } else {
#pragma unroll
      for (int j = 0; j < 8; ++j) v[j] = 0;
    }
    *(short8*)(xe0 + (long)b * 1280 + k) = v;
  } else {
    const int i = idx - 1024 * 160;
    if (i < 1024 * 128) {
      const int b = i >> 7;
      const int k = 1024 + (i & 127) * 8;
      short8 v;
#pragma unroll
      for (int j = 0; j < 8; ++j) v[j] = 0;
      *(short8*)(xe1 + (long)b * 2048 + k) = v;
    }
  }
}

extern "C" void kernel_launch(void* const* d_in, const int* in_sizes, int n_in,
                              void* d_out, int out_size, void* d_ws, size_t ws_size,
                              hipStream_t stream) {
  (void)in_sizes; (void)n_in; (void)out_size; (void)ws_size;
  const int* src = (const int*)d_in[0];
  const int* tgt = (const int*)d_in[1];
  const float* enc_emb = (const float*)d_in[2];
  const float* eW0i = (const float*)d_in[3];
  const float* eW0h = (const float*)d_in[4];
  const float* eb0 = (const float*)d_in[5];
  const float* eW1i = (const float*)d_in[6];
  const float* eW1h = (const float*)d_in[7];
  const float* eb1 = (const float*)d_in[8];
  const float* dec_emb = (const float*)d_in[9];
  const float* dW0i = (const float*)d_in[10];
  const float* dW0h = (const float*)d_in[11];
  const float* db0 = (const float*)d_in[12];
  const float* dW1i = (const float*)d_in[13];
  const float* dW1h = (const float*)d_in[14];
  const float* db1 = (const float*)d_in[15];
  const float* fcW = (const float*)d_in[16];
  const float* fcb = (const float*)d_in[17];
  float* out = (float*)d_out;

  char* ws = (char*)d_ws;
  size_t off = 0;
  auto carve = [&](size_t bytes) {
    void* p = ws + off;
    off += (bytes + 255) & ~(size_t)255;
    return p;
  };
  short* wc_e0 = (short*)carve(4096l * 1280 * 2);
  short* wc_e1 = (short*)carve(4096l * 2048 * 2);
  short* wc_d0 = (short*)carve(4096l * 1280 * 2);
  short* wc_d1 = (short*)carve(4096l * 2048 * 2);
  short* fcwt = (short*)carve(256l * 1024 * 2);
  short* embe = (short*)carve(256l * 256 * 2);
  short* embd = (short*)carve(256l * 256 * 2);
  short* xe0 = (short*)carve(2l * 1024 * 1280 * 2);
  short* xe1 = (short*)carve(2l * 1024 * 2048 * 2);
  short* xd0 = (short*)carve(2l * 1024 * 1280 * 2);
  short* xd1 = (short*)carve(2l * 1024 * 2048 * 2);
  short* dh1 = (short*)carve(47l * 1024 * 1024 * 2);
  const size_t flagbytes = 2l * 79 * 8 * 32 * 4;
  unsigned* flags = (unsigned*)carve(flagbytes);

  hipMemsetAsync(flags, 0, flagbytes, stream);
  hipMemsetAsync(out, 0, 1024l * 256 * 4, stream);  // outputs[0] stays zeros

  wprep<<<2560, 256, 0, stream>>>(eW0i, eW0h, wc_e0, 4096, 256, 1024);
  wprep<<<4096, 256, 0, stream>>>(eW1i, eW1h, wc_e1, 4096, 1024, 1024);
  wprep<<<2560, 256, 0, stream>>>(dW0i, dW0h, wc_d0, 4096, 256, 1024);
  wprep<<<4096, 256, 0, stream>>>(dW1i, dW1h, wc_d1, 4096, 1024, 1024);
  embprep<<<32, 256, 0, stream>>>(enc_emb, embe, 8192);
  embprep<<<32, 256, 0, stream>>>(dec_emb, embd, 8192);
  fcwprep<<<128, 256, 0, stream>>>(fcW, fcwt);
  initk<<<1152, 256, 0, stream>>>(src, enc_emb, xe0, xe1);

  pers_kernel<<<dim3(64, 8), 256, 0, stream>>>(
      xe0, xe1, xd0, xd1, wc_e0, wc_e1, wc_d0, wc_d1,
      eb0, eb1, db0, db1, embe, embd, src, tgt, dh1, flags);

  fc_kernel<<<dim3(2, 376), 256, 0, stream>>>(dh1, fcwt, fcb, out + 1024l * 256);
}